// Round 3
// baseline (7573.902 us; speedup 1.0000x reference)
//
#include <hip/hip_runtime.h>

static constexpr int KIN   = 25;
static constexpr int KOUT  = 5;
static constexpr int NCOPY = 8;   // one accumulator copy per XCD
static constexpr int PSTR  = 8;   // pack stride in floats (32B -> single cacheline)

// Physical XCD id of the CU this block runs on (gfx940+; measured on MI355X).
__device__ __forceinline__ int xcc_id() {
    int x;
    asm volatile("s_getreg_b32 %0, hwreg(HW_REG_XCC_ID)" : "=s"(x));
    return x & (NCOPY - 1);
}

// ---------------------------------------------------------------------------
// Kernel 1: per-node transforms xl = x@Wl, xr = x@Wr (stride-8 padded), plus
// self-loop contribution as the INITIALIZER of pack copy 0:
//   pack[0][node] = [w*xl0 .. w*xl4, w, _, _]   (w = exp(selfloop logit))
// Copies 1..NCOPY-1 are zeroed (MULTI path).
// ---------------------------------------------------------------------------
template <bool MULTI>
__global__ __launch_bounds__(256) void k_node(
    const float* __restrict__ x,
    const float* __restrict__ Wl, const float* __restrict__ Wr,
    const float* __restrict__ att,
    float* __restrict__ xl8, float* __restrict__ xr8,
    float* __restrict__ pack, int n)
{
    __shared__ float sWl[KIN * KOUT];
    __shared__ float sWr[KIN * KOUT];
    __shared__ float sAtt[KOUT];
    __shared__ float sx[256 * KIN];

    const int tid = threadIdx.x;
    if (tid < KIN * KOUT) { sWl[tid] = Wl[tid]; sWr[tid] = Wr[tid]; }
    if (tid < KOUT) sAtt[tid] = att[tid];

    const int base = blockIdx.x * 256;
    const int cnt  = min(256, n - base);
    const size_t xbase = (size_t)base * KIN;
    for (int i = tid; i < cnt * KIN; i += 256) sx[i] = x[xbase + i];
    __syncthreads();

    if (tid >= cnt) return;
    const int node = base + tid;

    float xls[KOUT] = {0.f, 0.f, 0.f, 0.f, 0.f};
    float xrs[KOUT] = {0.f, 0.f, 0.f, 0.f, 0.f};
    const float* xp = &sx[tid * KIN];
#pragma unroll
    for (int i = 0; i < KIN; ++i) {
        const float xv = xp[i];
#pragma unroll
        for (int o = 0; o < KOUT; ++o) {
            xls[o] += xv * sWl[i * KOUT + o];
            xrs[o] += xv * sWr[i * KOUT + o];
        }
    }

    float e = 0.f;
#pragma unroll
    for (int o = 0; o < KOUT; ++o) {
        float s = xls[o] + xrs[o];
        s = (s >= 0.f) ? s : 0.2f * s;
        e += s * sAtt[o];
    }
    const float w = __expf(e);

    const size_t n8 = (size_t)node * 8;
    float4 v4;
    v4.x = xls[0]; v4.y = xls[1]; v4.z = xls[2]; v4.w = xls[3];
    *(float4*)(xl8 + n8) = v4;
    xl8[n8 + 4] = xls[4];
    v4.x = xrs[0]; v4.y = xrs[1]; v4.z = xrs[2]; v4.w = xrs[3];
    *(float4*)(xr8 + n8) = v4;
    xr8[n8 + 4] = xrs[4];

    const size_t np = (size_t)node * PSTR;
    float4 a, b;
    a.x = w * xls[0]; a.y = w * xls[1]; a.z = w * xls[2]; a.w = w * xls[3];
    b.x = w * xls[4]; b.y = w;          b.z = 0.f;        b.w = 0.f;
    *(float4*)(pack + np)     = a;
    *(float4*)(pack + np + 4) = b;

    if (MULTI) {
        const float4 z = {0.f, 0.f, 0.f, 0.f};
        const size_t stride = (size_t)n * PSTR;
#pragma unroll
        for (int c = 1; c < NCOPY; ++c) {
            *(float4*)(pack + c * stride + np)     = z;
            *(float4*)(pack + c * stride + np + 4) = z;
        }
    }
}

// ---------------------------------------------------------------------------
// Kernel 2: per-edge attention + accumulation.
// MULTI: workgroup-scope atomics into this XCD's private copy (execute in the
// local L2 — all updates to a copy route through one L2, so atomicity holds
// regardless of block->XCD mapping). Else: device-scope into copy 0.
// ---------------------------------------------------------------------------
template <bool MULTI>
__global__ __launch_bounds__(256) void k_edge(
    const int* __restrict__ ei, int E,
    const float* __restrict__ xl8, const float* __restrict__ xr8,
    const float* __restrict__ att,
    float* __restrict__ pack, int n)
{
    const int e = blockIdx.x * 256 + threadIdx.x;
    if (e >= E) return;

    float* mypack = pack;
    if (MULTI) mypack += (size_t)xcc_id() * n * PSTR;

    const int s = ei[e];         // source j
    const int d = ei[E + e];     // target i

    const float a0 = att[0], a1 = att[1], a2 = att[2], a3 = att[3], a4 = att[4];

    const size_t s8 = (size_t)s * 8;
    const size_t d8 = (size_t)d * 8;
    const float4 xs = *(const float4*)(xl8 + s8);
    const float  xs4 = xl8[s8 + 4];
    const float4 xd = *(const float4*)(xr8 + d8);
    const float  xd4 = xr8[d8 + 4];

    float t, logit = 0.f;
    t = xs.x + xd.x; t = (t >= 0.f) ? t : 0.2f * t; logit += t * a0;
    t = xs.y + xd.y; t = (t >= 0.f) ? t : 0.2f * t; logit += t * a1;
    t = xs.z + xd.z; t = (t >= 0.f) ? t : 0.2f * t; logit += t * a2;
    t = xs.w + xd.w; t = (t >= 0.f) ? t : 0.2f * t; logit += t * a3;
    t = xs4  + xd4;  t = (t >= 0.f) ? t : 0.2f * t; logit += t * a4;

    const float w = __expf(logit);

    float* pp = mypack + (size_t)d * PSTR;
    if (MULTI) {
#pragma unroll
        for (int o = 0; o < 4; ++o) {
            float v = w * ((const float*)&xs)[o];
            __hip_atomic_fetch_add(pp + o, v, __ATOMIC_RELAXED, __HIP_MEMORY_SCOPE_WORKGROUP);
        }
        __hip_atomic_fetch_add(pp + 4, w * xs4, __ATOMIC_RELAXED, __HIP_MEMORY_SCOPE_WORKGROUP);
        __hip_atomic_fetch_add(pp + 5, w,       __ATOMIC_RELAXED, __HIP_MEMORY_SCOPE_WORKGROUP);
    } else {
        atomicAdd(pp + 0, w * xs.x);
        atomicAdd(pp + 1, w * xs.y);
        atomicAdd(pp + 2, w * xs.z);
        atomicAdd(pp + 3, w * xs.w);
        atomicAdd(pp + 4, w * xs4);
        atomicAdd(pp + 5, w);
    }
}

// ---------------------------------------------------------------------------
// Kernel 3: finalize one relation: sum copies, divide, bias, LeakyReLU(0.1)
// ---------------------------------------------------------------------------
template <bool MULTI>
__global__ __launch_bounds__(256) void k_fin(
    const float* __restrict__ pack, float* __restrict__ xout,
    const float* __restrict__ b, int n)
{
    const int node = blockIdx.x * 256 + threadIdx.x;
    if (node >= n) return;

    const size_t np = (size_t)node * PSTR;
    float num0 = 0.f, num1 = 0.f, num2 = 0.f, num3 = 0.f, num4 = 0.f, den = 0.f;
    const int nc = MULTI ? NCOPY : 1;
    const size_t stride = (size_t)n * PSTR;
#pragma unroll
    for (int c = 0; c < (MULTI ? NCOPY : 1); ++c) {
        const float* pp = pack + (size_t)c * stride + np;
        const float4 a = *(const float4*)(pp);
        const float2 bb = *(const float2*)(pp + 4);
        num0 += a.x; num1 += a.y; num2 += a.z; num3 += a.w;
        num4 += bb.x; den += bb.y;
    }
    (void)nc;

    const float inv = 1.0f / den;
    const float b0 = b[0], b1 = b[1], b2 = b[2], b3 = b[3], b4 = b[4];
    const size_t n5 = (size_t)node * KOUT;
    float v;
    v = num0 * inv + b0; xout[n5 + 0] = (v >= 0.f) ? v : 0.1f * v;
    v = num1 * inv + b1; xout[n5 + 1] = (v >= 0.f) ? v : 0.1f * v;
    v = num2 * inv + b2; xout[n5 + 2] = (v >= 0.f) ? v : 0.1f * v;
    v = num3 * inv + b3; xout[n5 + 3] = (v >= 0.f) ? v : 0.1f * v;
    v = num4 * inv + b4; xout[n5 + 4] = (v >= 0.f) ? v : 0.1f * v;
}

// ---------------------------------------------------------------------------
// Kernel 4: fused projection + classifier MLP.
// ---------------------------------------------------------------------------
__global__ __launch_bounds__(256) void k_mlp(
    const float* __restrict__ xp, const float* __restrict__ xs,
    const float* __restrict__ xv,
    const float* __restrict__ Wp1, const float* __restrict__ bp1,
    const float* __restrict__ Wp2, const float* __restrict__ bp2,
    const float* __restrict__ Wc1, const float* __restrict__ bc1,
    const float* __restrict__ Wc2, const float* __restrict__ bc2,
    float* __restrict__ out, int n)
{
    __shared__ float sW[257];
    const int tid = threadIdx.x;
    if (tid < 150) sW[tid] = Wp1[tid];
    if (tid < 10)  sW[150 + tid] = bp1[tid];
    if (tid < 50)  sW[160 + tid] = Wp2[tid];
    if (tid < 5)   sW[210 + tid] = bp2[tid];
    if (tid < 25)  sW[215 + tid] = Wc1[tid];
    if (tid < 5)   sW[240 + tid] = bc1[tid];
    if (tid < 10)  sW[245 + tid] = Wc2[tid];
    if (tid < 2)   sW[255 + tid] = bc2[tid];
    __syncthreads();

    const int node = blockIdx.x * 256 + tid;
    if (node >= n) return;
    const size_t n5 = (size_t)node * KOUT;

    float h[15];
#pragma unroll
    for (int k = 0; k < 5; ++k) {
        h[k]      = xp[n5 + k];
        h[5 + k]  = xs[n5 + k];
        h[10 + k] = xv[n5 + k];
    }

    float t1[10];
#pragma unroll
    for (int o = 0; o < 10; ++o) {
        float a = sW[150 + o];
#pragma unroll
        for (int i = 0; i < 15; ++i) a += h[i] * sW[i * 10 + o];
        t1[o] = (a >= 0.f) ? a : 0.1f * a;
    }

    float t2[5];
#pragma unroll
    for (int o = 0; o < 5; ++o) {
        float a = sW[210 + o];
#pragma unroll
        for (int i = 0; i < 10; ++i) a += t1[i] * sW[160 + i * 5 + o];
        t2[o] = a;
    }

    float t3[5];
#pragma unroll
    for (int o = 0; o < 5; ++o) {
        float a = sW[240 + o];
#pragma unroll
        for (int i = 0; i < 5; ++i) a += t2[i] * sW[215 + i * 5 + o];
        t3[o] = (a >= 0.f) ? a : 0.1f * a;
    }

    float o0 = sW[255], o1 = sW[256];
#pragma unroll
    for (int i = 0; i < 5; ++i) {
        o0 += t3[i] * sW[245 + i * 2 + 0];
        o1 += t3[i] * sW[245 + i * 2 + 1];
    }
    out[(size_t)node * 2 + 0] = o0;
    out[(size_t)node * 2 + 1] = o1;
}

// ---------------------------------------------------------------------------
extern "C" void kernel_launch(void* const* d_in, const int* in_sizes, int n_in,
                              void* d_out, int out_size, void* d_ws, size_t ws_size,
                              hipStream_t stream)
{
    const float* x = (const float*)d_in[0];
    const int n = in_sizes[0] / KIN;          // 1,000,000
    const int E = in_sizes[1] / 2;            // 8,000,000

    const int* ei[3] = { (const int*)d_in[1], (const int*)d_in[2], (const int*)d_in[3] };
    const float *Wl[3], *Wr[3], *att[3], *bias[3];
    for (int r = 0; r < 3; ++r) {
        const int base = 4 + r * 4;
        Wl[r]   = (const float*)d_in[base + 0];
        Wr[r]   = (const float*)d_in[base + 1];
        att[r]  = (const float*)d_in[base + 2];
        bias[r] = (const float*)d_in[base + 3];
    }
    const float* Wp1 = (const float*)d_in[16];
    const float* bp1 = (const float*)d_in[17];
    const float* Wp2 = (const float*)d_in[18];
    const float* bp2 = (const float*)d_in[19];
    const float* Wc1 = (const float*)d_in[20];
    const float* bc1 = (const float*)d_in[21];
    const float* Wc2 = (const float*)d_in[22];
    const float* bc2 = (const float*)d_in[23];

    // workspace layout (floats):
    //   xout[3][n][5] | xl8[n][8] | xr8[n][8] | pack[NC][n][8]
    float* ws   = (float*)d_ws;
    float* xout = ws;
    float* xl8  = ws  + (size_t)15 * n;
    float* xr8  = xl8 + (size_t)8 * n;
    float* pack = xr8 + (size_t)8 * n;

    const size_t need_multi = ((size_t)31 * n + (size_t)NCOPY * PSTR * n) * 4;
    const bool multi = ws_size >= need_multi;

    const int nb_node = (n + 255) / 256;
    const int nb_edge = (E + 255) / 256;

    for (int r = 0; r < 3; ++r) {
        float* xo = xout + (size_t)r * 5 * n;
        if (multi) {
            k_node<true><<<nb_node, 256, 0, stream>>>(x, Wl[r], Wr[r], att[r],
                                                      xl8, xr8, pack, n);
            k_edge<true><<<nb_edge, 256, 0, stream>>>(ei[r], E, xl8, xr8, att[r], pack, n);
            k_fin<true><<<nb_node, 256, 0, stream>>>(pack, xo, bias[r], n);
        } else {
            k_node<false><<<nb_node, 256, 0, stream>>>(x, Wl[r], Wr[r], att[r],
                                                       xl8, xr8, pack, n);
            k_edge<false><<<nb_edge, 256, 0, stream>>>(ei[r], E, xl8, xr8, att[r], pack, n);
            k_fin<false><<<nb_node, 256, 0, stream>>>(pack, xo, bias[r], n);
        }
    }

    k_mlp<<<nb_node, 256, 0, stream>>>(xout, xout + (size_t)5 * n, xout + (size_t)10 * n,
                                       Wp1, bp1, Wp2, bp2, Wc1, bc1, Wc2, bc2,
                                       (float*)d_out, n);
}

// Round 4
// 1718.317 us; speedup vs baseline: 4.4077x; 4.4077x over previous
//
#include <hip/hip_runtime.h>

static constexpr int KIN  = 25;
static constexpr int KOUT = 5;
static constexpr int NBLK = 256;      // blocks for hist/scatter
static constexpr int BSH  = 10;       // log2 nodes per bucket
static constexpr int NPB  = 1 << BSH; // 1024 nodes per bucket

// ---------------------------------------------------------------------------
// k_node: xl = x@Wl (stride 8, aligned for float4 gathers), xr = x@Wr (stride 5)
// ---------------------------------------------------------------------------
__global__ __launch_bounds__(256) void k_node(
    const float* __restrict__ x,
    const float* __restrict__ Wl, const float* __restrict__ Wr,
    float* __restrict__ xl8, float* __restrict__ xr5, int n)
{
    __shared__ float sWl[KIN * KOUT];
    __shared__ float sWr[KIN * KOUT];
    __shared__ float sx[256 * KIN];

    const int tid = threadIdx.x;
    if (tid < KIN * KOUT) { sWl[tid] = Wl[tid]; sWr[tid] = Wr[tid]; }

    const int base = blockIdx.x * 256;
    const int cnt  = min(256, n - base);
    const size_t xbase = (size_t)base * KIN;
    for (int i = tid; i < cnt * KIN; i += 256) sx[i] = x[xbase + i];
    __syncthreads();

    if (tid >= cnt) return;
    const int node = base + tid;

    float xls[KOUT] = {0.f, 0.f, 0.f, 0.f, 0.f};
    float xrs[KOUT] = {0.f, 0.f, 0.f, 0.f, 0.f};
    const float* xp = &sx[tid * KIN];
#pragma unroll
    for (int i = 0; i < KIN; ++i) {
        const float xv = xp[i];
#pragma unroll
        for (int o = 0; o < KOUT; ++o) {
            xls[o] += xv * sWl[i * KOUT + o];
            xrs[o] += xv * sWr[i * KOUT + o];
        }
    }

    const size_t n8 = (size_t)node * 8;
    float4 v4;
    v4.x = xls[0]; v4.y = xls[1]; v4.z = xls[2]; v4.w = xls[3];
    *(float4*)(xl8 + n8) = v4;
    xl8[n8 + 4] = xls[4];

    const size_t n5 = (size_t)node * 5;
#pragma unroll
    for (int o = 0; o < KOUT; ++o) xr5[n5 + o] = xrs[o];
}

// ---------------------------------------------------------------------------
// k_hist: per-block bucket histogram of dst (no global atomics).
// ---------------------------------------------------------------------------
__global__ __launch_bounds__(256) void k_hist(
    const int* __restrict__ dst, int E, int NB,
    int* __restrict__ hist_blk)
{
    __shared__ int h[1024];
    const int b = blockIdx.x, tid = threadIdx.x;
    for (int i = tid; i < NB; i += 256) h[i] = 0;
    __syncthreads();
    const int chunk = (E + NBLK - 1) / NBLK;
    const int eb = b * chunk, ee = min(E, eb + chunk);
    for (int i = eb + tid; i < ee; i += 256)
        atomicAdd(&h[dst[i] >> BSH], 1);
    __syncthreads();
    for (int i = tid; i < NB; i += 256) hist_blk[b * NB + i] = h[i];
}

// ---------------------------------------------------------------------------
// k_scan: one block. Column-sum hist_blk -> totals; exclusive scan -> base,
// cursor. base[NB] = E.
// ---------------------------------------------------------------------------
__global__ __launch_bounds__(1024) void k_scan(
    const int* __restrict__ hist_blk, int E, int NB,
    int* __restrict__ base, int* __restrict__ cursor)
{
    __shared__ int s[1024];
    const int t = threadIdx.x;
    int tot = 0;
    if (t < NB)
        for (int b = 0; b < NBLK; ++b) tot += hist_blk[b * NB + t];
    s[t] = tot;
    __syncthreads();
    for (int off = 1; off < 1024; off <<= 1) {
        int v = (t >= off) ? s[t - off] : 0;
        __syncthreads();
        s[t] += v;
        __syncthreads();
    }
    if (t < NB) {
        const int b0 = s[t] - tot;     // exclusive prefix
        base[t]   = b0;
        cursor[t] = b0;
    }
    if (t == 0) base[NB] = E;
}

// ---------------------------------------------------------------------------
// k_scatter: reserve disjoint per-(block,bucket) ranges via cursor atomics,
// then scatter edges packed as (src << BSH) | (dst & (NPB-1)).
// ---------------------------------------------------------------------------
__global__ __launch_bounds__(256) void k_scatter(
    const int* __restrict__ src, const int* __restrict__ dst, int E, int NB,
    int* __restrict__ cursor, int* __restrict__ rs)
{
    __shared__ int h[1024];
    __shared__ int cur[1024];
    const int b = blockIdx.x, tid = threadIdx.x;
    for (int i = tid; i < NB; i += 256) h[i] = 0;
    __syncthreads();
    const int chunk = (E + NBLK - 1) / NBLK;
    const int eb = b * chunk, ee = min(E, eb + chunk);
    for (int i = eb + tid; i < ee; i += 256)
        atomicAdd(&h[dst[i] >> BSH], 1);
    __syncthreads();
    for (int i = tid; i < NB; i += 256)
        cur[i] = (h[i] > 0) ? atomicAdd(&cursor[i], h[i]) : 0;
    __syncthreads();
    for (int i = eb + tid; i < ee; i += 256) {
        const int d = dst[i];
        const int bkt = d >> BSH;
        const int pos = atomicAdd(&cur[bkt], 1);          // LDS atomic
        rs[pos] = (src[i] << BSH) | (d & (NPB - 1));
    }
}

// ---------------------------------------------------------------------------
// k_gather: one block per bucket. LDS accumulator acc[1024][6]; per edge:
// gather xl8[src] (LLC), xr5[dst] (L2 window), 6x ds_add_f32. Epilogue folds
// the self-loop, divides, adds bias, LeakyReLU(0.1), writes xout.
// ---------------------------------------------------------------------------
__global__ __launch_bounds__(256) void k_gather(
    const int* __restrict__ rs, const int* __restrict__ base,
    const float* __restrict__ xl8, const float* __restrict__ xr5,
    const float* __restrict__ att, const float* __restrict__ bias,
    float* __restrict__ xout, int n)
{
    __shared__ float acc[NPB][6];
    const int bkt = blockIdx.x, tid = threadIdx.x;
    for (int i = tid; i < NPB * 6; i += 256) ((float*)acc)[i] = 0.f;

    const float a0 = att[0], a1 = att[1], a2 = att[2], a3 = att[3], a4 = att[4];
    const int node0 = bkt << BSH;
    __syncthreads();

    const int eb = base[bkt], ee = base[bkt + 1];
    for (int i = eb + tid; i < ee; i += 256) {
        const int v  = rs[i];
        const int s  = v >> BSH;
        const int dl = v & (NPB - 1);

        const size_t s8 = (size_t)s * 8;
        const float4 xs = *(const float4*)(xl8 + s8);
        const float  xs4 = xl8[s8 + 4];
        const size_t d5 = (size_t)(node0 + dl) * 5;

        float t, logit = 0.f;
        t = xs.x + xr5[d5 + 0]; t = (t >= 0.f) ? t : 0.2f * t; logit += t * a0;
        t = xs.y + xr5[d5 + 1]; t = (t >= 0.f) ? t : 0.2f * t; logit += t * a1;
        t = xs.z + xr5[d5 + 2]; t = (t >= 0.f) ? t : 0.2f * t; logit += t * a2;
        t = xs.w + xr5[d5 + 3]; t = (t >= 0.f) ? t : 0.2f * t; logit += t * a3;
        t = xs4  + xr5[d5 + 4]; t = (t >= 0.f) ? t : 0.2f * t; logit += t * a4;

        const float w = __expf(logit);
        atomicAdd(&acc[dl][0], w * xs.x);
        atomicAdd(&acc[dl][1], w * xs.y);
        atomicAdd(&acc[dl][2], w * xs.z);
        atomicAdd(&acc[dl][3], w * xs.w);
        atomicAdd(&acc[dl][4], w * xs4);
        atomicAdd(&acc[dl][5], w);
    }
    __syncthreads();

    const float b0 = bias[0], b1 = bias[1], b2 = bias[2], b3 = bias[3], b4 = bias[4];
    for (int l = tid; l < NPB; l += 256) {
        const int node = node0 + l;
        if (node >= n) break;
        const size_t s8 = (size_t)node * 8;
        const float4 xs = *(const float4*)(xl8 + s8);
        const float  xs4 = xl8[s8 + 4];
        const size_t d5 = (size_t)node * 5;

        float t, logit = 0.f;                 // self-loop logit
        t = xs.x + xr5[d5 + 0]; t = (t >= 0.f) ? t : 0.2f * t; logit += t * a0;
        t = xs.y + xr5[d5 + 1]; t = (t >= 0.f) ? t : 0.2f * t; logit += t * a1;
        t = xs.z + xr5[d5 + 2]; t = (t >= 0.f) ? t : 0.2f * t; logit += t * a2;
        t = xs.w + xr5[d5 + 3]; t = (t >= 0.f) ? t : 0.2f * t; logit += t * a3;
        t = xs4  + xr5[d5 + 4]; t = (t >= 0.f) ? t : 0.2f * t; logit += t * a4;
        const float w = __expf(logit);

        const float inv = 1.0f / (acc[l][5] + w);
        float v;
        v = (acc[l][0] + w * xs.x) * inv + b0; xout[d5 + 0] = (v >= 0.f) ? v : 0.1f * v;
        v = (acc[l][1] + w * xs.y) * inv + b1; xout[d5 + 1] = (v >= 0.f) ? v : 0.1f * v;
        v = (acc[l][2] + w * xs.z) * inv + b2; xout[d5 + 2] = (v >= 0.f) ? v : 0.1f * v;
        v = (acc[l][3] + w * xs.w) * inv + b3; xout[d5 + 3] = (v >= 0.f) ? v : 0.1f * v;
        v = (acc[l][4] + w * xs4 ) * inv + b4; xout[d5 + 4] = (v >= 0.f) ? v : 0.1f * v;
    }
}

// ---------------------------------------------------------------------------
// k_mlp: fused projection + classifier.
// ---------------------------------------------------------------------------
__global__ __launch_bounds__(256) void k_mlp(
    const float* __restrict__ xp, const float* __restrict__ xs,
    const float* __restrict__ xv,
    const float* __restrict__ Wp1, const float* __restrict__ bp1,
    const float* __restrict__ Wp2, const float* __restrict__ bp2,
    const float* __restrict__ Wc1, const float* __restrict__ bc1,
    const float* __restrict__ Wc2, const float* __restrict__ bc2,
    float* __restrict__ out, int n)
{
    __shared__ float sW[257];
    const int tid = threadIdx.x;
    if (tid < 150) sW[tid] = Wp1[tid];
    if (tid < 10)  sW[150 + tid] = bp1[tid];
    if (tid < 50)  sW[160 + tid] = Wp2[tid];
    if (tid < 5)   sW[210 + tid] = bp2[tid];
    if (tid < 25)  sW[215 + tid] = Wc1[tid];
    if (tid < 5)   sW[240 + tid] = bc1[tid];
    if (tid < 10)  sW[245 + tid] = Wc2[tid];
    if (tid < 2)   sW[255 + tid] = bc2[tid];
    __syncthreads();

    const int node = blockIdx.x * 256 + tid;
    if (node >= n) return;
    const size_t n5 = (size_t)node * KOUT;

    float h[15];
#pragma unroll
    for (int k = 0; k < 5; ++k) {
        h[k]      = xp[n5 + k];
        h[5 + k]  = xs[n5 + k];
        h[10 + k] = xv[n5 + k];
    }

    float t1[10];
#pragma unroll
    for (int o = 0; o < 10; ++o) {
        float a = sW[150 + o];
#pragma unroll
        for (int i = 0; i < 15; ++i) a += h[i] * sW[i * 10 + o];
        t1[o] = (a >= 0.f) ? a : 0.1f * a;
    }

    float t2[5];
#pragma unroll
    for (int o = 0; o < 5; ++o) {
        float a = sW[210 + o];
#pragma unroll
        for (int i = 0; i < 10; ++i) a += t1[i] * sW[160 + i * 5 + o];
        t2[o] = a;
    }

    float t3[5];
#pragma unroll
    for (int o = 0; o < 5; ++o) {
        float a = sW[240 + o];
#pragma unroll
        for (int i = 0; i < 5; ++i) a += t2[i] * sW[215 + i * 5 + o];
        t3[o] = (a >= 0.f) ? a : 0.1f * a;
    }

    float o0 = sW[255], o1 = sW[256];
#pragma unroll
    for (int i = 0; i < 5; ++i) {
        o0 += t3[i] * sW[245 + i * 2 + 0];
        o1 += t3[i] * sW[245 + i * 2 + 1];
    }
    out[(size_t)node * 2 + 0] = o0;
    out[(size_t)node * 2 + 1] = o1;
}

// ---------------------------------------------------------------------------
extern "C" void kernel_launch(void* const* d_in, const int* in_sizes, int n_in,
                              void* d_out, int out_size, void* d_ws, size_t ws_size,
                              hipStream_t stream)
{
    const float* x = (const float*)d_in[0];
    const int n = in_sizes[0] / KIN;          // 1,000,000
    const int E = in_sizes[1] / 2;            // 8,000,000
    const int NB = (n + NPB - 1) >> BSH;      // 977 buckets (requires n <= 2^20)

    const int* ei[3] = { (const int*)d_in[1], (const int*)d_in[2], (const int*)d_in[3] };
    const float *Wl[3], *Wr[3], *att[3], *bias[3];
    for (int r = 0; r < 3; ++r) {
        const int base = 4 + r * 4;
        Wl[r]   = (const float*)d_in[base + 0];
        Wr[r]   = (const float*)d_in[base + 1];
        att[r]  = (const float*)d_in[base + 2];
        bias[r] = (const float*)d_in[base + 3];
    }
    const float* Wp1 = (const float*)d_in[16];
    const float* bp1 = (const float*)d_in[17];
    const float* Wp2 = (const float*)d_in[18];
    const float* bp2 = (const float*)d_in[19];
    const float* Wc1 = (const float*)d_in[20];
    const float* bc1 = (const float*)d_in[21];
    const float* Wc2 = (const float*)d_in[22];
    const float* bc2 = (const float*)d_in[23];

    // ws layout (4B units), ~145 MB total:
    //   xout[3][n][5] | xl8[n][8] | xr5[n][5] | rs[E] | hist_blk[NBLK*NB] |
    //   base[NB+1] | cursor[NB]
    float* ws   = (float*)d_ws;
    float* xout = ws;
    float* xl8  = ws  + (size_t)15 * n;
    float* xr5  = xl8 + (size_t)8 * n;
    int*   rs   = (int*)(xr5 + (size_t)5 * n);
    int*   hist_blk = rs + (size_t)E;
    int*   base     = hist_blk + (size_t)NBLK * NB;
    int*   cursor   = base + NB + 1;

    const int nb_node = (n + 255) / 256;

    for (int r = 0; r < 3; ++r) {
        float* xo = xout + (size_t)r * 5 * n;
        const int* src = ei[r];
        const int* dst = ei[r] + E;

        k_hist   <<<NBLK,    256,  0, stream>>>(dst, E, NB, hist_blk);
        k_scan   <<<1,       1024, 0, stream>>>(hist_blk, E, NB, base, cursor);
        k_scatter<<<NBLK,    256,  0, stream>>>(src, dst, E, NB, cursor, rs);
        k_node   <<<nb_node, 256,  0, stream>>>(x, Wl[r], Wr[r], xl8, xr5, n);
        k_gather <<<NB,      256,  0, stream>>>(rs, base, xl8, xr5, att[r], bias[r],
                                                xo, n);
    }

    k_mlp<<<nb_node, 256, 0, stream>>>(xout, xout + (size_t)5 * n, xout + (size_t)10 * n,
                                       Wp1, bp1, Wp2, bp2, Wc1, bc1, Wc2, bc2,
                                       (float*)d_out, n);
}